// Round 10
// baseline (325.817 us; speedup 1.0000x reference)
//
#include <hip/hip_runtime.h>

#define T_SEQ 2048
#define NHEAD 16
#define HD 64
#define CDIM 1024

typedef __bf16 bf16x8 __attribute__((ext_vector_type(8)));
typedef float f32x4 __attribute__((ext_vector_type(4)));

union U16x8 { uint4 u4; unsigned short s[8]; bf16x8 b; };

__device__ __forceinline__ float bf2f(unsigned short u) {
    return __uint_as_float(((unsigned int)u) << 16);
}
__device__ __forceinline__ unsigned short f2bf(float f) {
    unsigned int u = __float_as_uint(f);
    u += 0x7fffu + ((u >> 16) & 1u);   // round-to-nearest-even
    return (unsigned short)(u >> 16);
}
__device__ __forceinline__ unsigned short f2bf_fast(float f) {   // round-half-up
    return (unsigned short)((__float_as_uint(f) + 0x8000u) >> 16);
}
__device__ __forceinline__ U16x8 load8f(const float* __restrict__ p) {
    U16x8 r;
    float4 f0 = *(const float4*)p;
    float4 f1 = *(const float4*)(p + 4);
    r.s[0] = f2bf(f0.x); r.s[1] = f2bf(f0.y); r.s[2] = f2bf(f0.z); r.s[3] = f2bf(f0.w);
    r.s[4] = f2bf(f1.x); r.s[5] = f2bf(f1.y); r.s[6] = f2bf(f1.z); r.s[7] = f2bf(f1.w);
    return r;
}

#define LOG2E 1.442695040f

// ---------------------------------------------------------------------------
// Conversion pass
// ---------------------------------------------------------------------------
__global__ __launch_bounds__(256) void conv_bf16(
    const float* __restrict__ in, unsigned short* __restrict__ out, int n)
{
    const int i = (blockIdx.x * 256 + threadIdx.x) * 8;
    if (i < n) {
        U16x8 o = load8f(&in[i]);
        *(uint4*)&out[i] = o.u4;
    }
}

// in: [R,C] fp32 -> out: [C,R] bf16.  R,C multiples of 64.
__global__ __launch_bounds__(256) void transpose_conv(
    const float* __restrict__ in, unsigned short* __restrict__ out, int R, int C)
{
    __shared__ float tile[64][65];
    const int r0 = blockIdx.x * 64;
    const int c0 = blockIdx.y * 64;
    const int tid = threadIdx.x;
    const int rr = tid >> 4;
    const int cc = (tid & 15) * 4;
#pragma unroll
    for (int p = 0; p < 4; ++p) {
        float4 v = *(const float4*)&in[(size_t)(r0 + p * 16 + rr) * C + c0 + cc];
        tile[p * 16 + rr][cc] = v.x;
        tile[p * 16 + rr][cc + 1] = v.y;
        tile[p * 16 + rr][cc + 2] = v.z;
        tile[p * 16 + rr][cc + 3] = v.w;
    }
    __syncthreads();
    const int n = tid >> 2;
    const int s = (tid & 3) * 8;
#pragma unroll
    for (int p = 0; p < 2; ++p) {
        const int k = s + p * 32;
        U16x8 o;
#pragma unroll
        for (int j = 0; j < 8; ++j) o.s[j] = f2bf(tile[k + j][n]);
        *(uint4*)&out[(size_t)(c0 + n) * R + r0 + k] = o.u4;
    }
}

// ---------------------------------------------------------------------------
// GEMM core with register-prefetch double buffering (flash-style staging):
// C[128x128] = A[M,K](bf16 rm) * Bt[N,K](bf16 rm)^T.  256 thr = 4 waves 2x2.
// Loads for tile kb+64 are issued right after the compute barrier and land in
// VGPRs; they overlap the 32 MFMAs + next barrier. No vmcnt(0) drain.
// ---------------------------------------------------------------------------
__device__ __forceinline__ void gemm128_core(
    const unsigned short* __restrict__ A,
    const unsigned short* __restrict__ Bt,
    int K, int m0, int n0,
    unsigned short* As, unsigned short* Bs, f32x4 acc[4][4])
{
    const int tid = threadIdx.x;
    const int w = tid >> 6, lane = tid & 63;
    const int ln = lane & 15, quad = lane >> 4;
    const int wm = w >> 1, wn = w & 1;
    const int lr = lane >> 3;        // 0..7
    const int lc = (lane & 7) * 8;   // col start (elems)
    const int arow = w * 32 + lr;    // this thread's 4 stage rows: arow + i*8

    // prologue: tile 0 -> regs
    uint4 ar[4], br[4];
#pragma unroll
    for (int i = 0; i < 4; ++i) {
        ar[i] = *(const uint4*)&A[(size_t)(m0 + arow + i * 8) * K + lc];
        br[i] = *(const uint4*)&Bt[(size_t)(n0 + arow + i * 8) * K + lc];
    }

    for (int kb = 0; kb < K; kb += 64) {
        __syncthreads();           // LDS free (previous compute done)
#pragma unroll
        for (int i = 0; i < 4; ++i) {
            *(uint4*)&As[(arow + i * 8) * 64 + lc] = ar[i];
            *(uint4*)&Bs[(arow + i * 8) * 64 + lc] = br[i];
        }
        __syncthreads();           // LDS ready

        if (kb + 64 < K) {         // prefetch next tile (overlaps MFMAs)
#pragma unroll
            for (int i = 0; i < 4; ++i) {
                ar[i] = *(const uint4*)&A[(size_t)(m0 + arow + i * 8) * K + kb + 64 + lc];
                br[i] = *(const uint4*)&Bt[(size_t)(n0 + arow + i * 8) * K + kb + 64 + lc];
            }
        }

#pragma unroll
        for (int kk = 0; kk < 2; ++kk) {
            U16x8 af[4], bff[4];
#pragma unroll
            for (int i = 0; i < 4; ++i)
                af[i].u4 = *(const uint4*)&As[(wm * 64 + i * 16 + ln) * 64 + kk * 32 + quad * 8];
#pragma unroll
            for (int j = 0; j < 4; ++j)
                bff[j].u4 = *(const uint4*)&Bs[(wn * 64 + j * 16 + ln) * 64 + kk * 32 + quad * 8];
#pragma unroll
            for (int i = 0; i < 4; ++i)
#pragma unroll
                for (int j = 0; j < 4; ++j)
                    acc[i][j] = __builtin_amdgcn_mfma_f32_16x16x32_bf16(af[i].b, bff[j].b, acc[i][j], 0, 0, 0);
        }
    }
}

// ---------------------------------------------------------------------------
// Kernel: Q/K GEMM + scatter to [B,H,T,hd].  n-tiles on blockIdx.x (XCD L2).
// ---------------------------------------------------------------------------
__global__ __launch_bounds__(256) void qk_gemm(
    const unsigned short* __restrict__ Xb,    // [4096,1024] bf16
    const unsigned short* __restrict__ Wt,    // [2048,1024] bf16 (Wq,Wk ^T)
    const float* __restrict__ bias,           // [3072] (first 2048 used)
    unsigned short* __restrict__ Qp,
    unsigned short* __restrict__ Kp)
{
    __shared__ unsigned short As[128 * 64];
    __shared__ unsigned short Bs[128 * 64];
    const int m0 = blockIdx.y * 128;
    const int n0 = blockIdx.x * 128;

    f32x4 acc[4][4];
#pragma unroll
    for (int i = 0; i < 4; ++i)
#pragma unroll
        for (int j = 0; j < 4; ++j) acc[i][j] = (f32x4){0.f, 0.f, 0.f, 0.f};

    gemm128_core(Xb, Wt, CDIM, m0, n0, As, Bs, acc);

    const int tid = threadIdx.x;
    const int w = tid >> 6, lane = tid & 63;
    const int ln = lane & 15, quad = lane >> 4;
    const int wm = w >> 1, wn = w & 1;

#pragma unroll
    for (int j = 0; j < 4; ++j) {
        const int n = n0 + wn * 64 + j * 16 + ln;
        const float bv = bias[n];
        const int which = n >> 10;          // 0=Q, 1=K
        const int h = (n >> 6) & 15, d = n & 63;
        unsigned short* dst = which == 0 ? Qp : Kp;
#pragma unroll
        for (int i = 0; i < 4; ++i)
#pragma unroll
            for (int r = 0; r < 4; ++r) {
                const int m = m0 + wm * 64 + i * 16 + quad * 4 + r;
                const int b = m >> 11, tt = m & 2047;
                dst[(((b * NHEAD + h) * T_SEQ) + tt) * HD + d] = f2bf(acc[i][j][r] + bv);
            }
    }
}

// ---------------------------------------------------------------------------
// Kernel: V^T GEMM.  Vt[(b,h,d), tt] = sum_k Wv^T[row,k] * Xb[tok,k] + bias.
// ---------------------------------------------------------------------------
__global__ __launch_bounds__(256) void vt_gemm(
    const unsigned short* __restrict__ WvT,   // [1024,1024] bf16
    const unsigned short* __restrict__ Xb,    // [4096,1024] bf16
    const float* __restrict__ biasv,          // [1024] (V part)
    unsigned short* __restrict__ Vtp)         // [B,H,hd,T] bf16
{
    __shared__ unsigned short As[128 * 64];
    __shared__ unsigned short Bs[128 * 64];
    const int m0 = blockIdx.y * 128;   // rows = h*64+d  (1024 -> 8)
    const int n0 = blockIdx.x * 128;   // tokens (4096 -> 32)

    f32x4 acc[4][4];
#pragma unroll
    for (int i = 0; i < 4; ++i)
#pragma unroll
        for (int j = 0; j < 4; ++j) acc[i][j] = (f32x4){0.f, 0.f, 0.f, 0.f};

    gemm128_core(WvT, Xb, CDIM, m0, n0, As, Bs, acc);

    const int tid = threadIdx.x;
    const int w = tid >> 6, lane = tid & 63;
    const int ln = lane & 15, quad = lane >> 4;
    const int wm = w >> 1, wn = w & 1;

#pragma unroll
    for (int i = 0; i < 4; ++i)
#pragma unroll
        for (int r = 0; r < 4; ++r) {
            const int row = m0 + wm * 64 + i * 16 + quad * 4 + r;   // h*64+d
            const float bv = biasv[row];
#pragma unroll
            for (int j = 0; j < 4; ++j) {
                const int n = n0 + wn * 64 + j * 16 + ln;           // global token
                const int b = n >> 11, tt = n & 2047;
                Vtp[(size_t)(b * 1024 + row) * T_SEQ + tt] = f2bf(acc[i][j][r] + bv);
            }
        }
}

// ---------------------------------------------------------------------------
// Kernel: proj GEMM -> fp32 out.  n-tiles on blockIdx.x (XCD L2).
// ---------------------------------------------------------------------------
__global__ __launch_bounds__(256) void proj_gemm(
    const unsigned short* __restrict__ Yin,   // [4096,1024] bf16
    const unsigned short* __restrict__ Wt,    // [1024,1024] bf16 (W^T)
    const float* __restrict__ bias,           // [1024]
    float* __restrict__ out)                  // [4096,1024] fp32
{
    __shared__ unsigned short As[128 * 64];
    __shared__ unsigned short Bs[128 * 64];
    const int m0 = blockIdx.y * 128;
    const int n0 = blockIdx.x * 128;

    f32x4 acc[4][4];
#pragma unroll
    for (int i = 0; i < 4; ++i)
#pragma unroll
        for (int j = 0; j < 4; ++j) acc[i][j] = (f32x4){0.f, 0.f, 0.f, 0.f};

    gemm128_core(Yin, Wt, CDIM, m0, n0, As, Bs, acc);

    const int tid = threadIdx.x;
    const int w = tid >> 6, lane = tid & 63;
    const int ln = lane & 15, quad = lane >> 4;
    const int wm = w >> 1, wn = w & 1;

#pragma unroll
    for (int j = 0; j < 4; ++j) {
        const int n = n0 + wn * 64 + j * 16 + ln;
        const float bv = bias[n];
#pragma unroll
        for (int i = 0; i < 4; ++i)
#pragma unroll
            for (int r = 0; r < 4; ++r) {
                const int m = m0 + wm * 64 + i * 16 + quad * 4 + r;
                out[(size_t)m * CDIM + n] = acc[i][j][r] + bv;
            }
    }
}

// ---------------------------------------------------------------------------
// MFMA flash attention (unchanged from round 9)
// ---------------------------------------------------------------------------
#define ATT_STRIDE 72

__global__ __launch_bounds__(256) void flash_attn(
    const unsigned short* __restrict__ Qp,   // [BH, T, 64]
    const unsigned short* __restrict__ Kp,   // [BH, T, 64]
    const unsigned short* __restrict__ Vtp,  // [BH, 64, T]
    const int* __restrict__ mask,            // [B, T]
    unsigned short* __restrict__ Y)          // [B*T, 1024] bf16
{
    __shared__ unsigned short Ks[64 * ATT_STRIDE];
    __shared__ unsigned short Vs[64 * ATT_STRIDE];
    __shared__ unsigned short Ps[64 * ATT_STRIDE];
    __shared__ float mask_f[64];

    const int bh = blockIdx.x;                       // XCD locality on K/V
    const int qt = (T_SEQ / 64 - 1) - blockIdx.y;    // heavy first
    const int b = bh >> 4, h = bh & 15;
    const int tid = threadIdx.x;
    const int w = tid >> 6, lane = tid & 63;
    const int ln = lane & 15, quad = lane >> 4;
    const int row8 = tid >> 3, seg = tid & 7;
    const size_t base = (size_t)bh * T_SEQ * HD;
    const int q0 = qt * 64;

    U16x8 qf[2];
    {
        const unsigned short* qrow = &Qp[base + (size_t)(q0 + w * 16 + ln) * HD];
        qf[0].u4 = *(const uint4*)&qrow[quad * 8];
        qf[1].u4 = *(const uint4*)&qrow[32 + quad * 8];
    }

    f32x4 o[4];
#pragma unroll
    for (int n = 0; n < 4; ++n) o[n] = (f32x4){0.f, 0.f, 0.f, 0.f};
    float m_i[4] = {-3.0e38f, -3.0e38f, -3.0e38f, -3.0e38f};
    float l_i[4] = {0.f, 0.f, 0.f, 0.f};   // per-lane PARTIAL sums

    // register prefetch of tile 0
    uint4 kr0, kr1, vr0, vr1;
    float mf = 0.f;
    {
        const unsigned short* kp0 = &Kp[base + (size_t)row8 * HD + seg * 8];
        kr0 = *(const uint4*)kp0;
        kr1 = *(const uint4*)(kp0 + 32 * HD);
        const unsigned short* vp0 = &Vtp[base + (size_t)row8 * T_SEQ + seg * 8];
        vr0 = *(const uint4*)vp0;
        vr1 = *(const uint4*)(vp0 + 32 * T_SEQ);
        if (tid < 64) mf = mask[b * T_SEQ + tid] ? 0.f : -1.0e30f;
    }

    for (int j = 0; j <= qt; ++j) {
        __syncthreads();
        *(uint4*)&Ks[row8 * ATT_STRIDE + seg * 8] = kr0;
        *(uint4*)&Ks[(row8 + 32) * ATT_STRIDE + seg * 8] = kr1;
        *(uint4*)&Vs[row8 * ATT_STRIDE + seg * 8] = vr0;
        *(uint4*)&Vs[(row8 + 32) * ATT_STRIDE + seg * 8] = vr1;
        if (tid < 64) mask_f[tid] = mf;
        __syncthreads();

        if (j < qt) {   // prefetch next tile
            const unsigned short* kp0 = &Kp[base + (size_t)((j + 1) * 64 + row8) * HD + seg * 8];
            kr0 = *(const uint4*)kp0;
            kr1 = *(const uint4*)(kp0 + 32 * HD);
            const unsigned short* vp0 = &Vtp[base + (size_t)row8 * T_SEQ + (j + 1) * 64 + seg * 8];
            vr0 = *(const uint4*)vp0;
            vr1 = *(const uint4*)(vp0 + 32 * T_SEQ);
            if (tid < 64) mf = mask[b * T_SEQ + (j + 1) * 64 + tid] ? 0.f : -1.0e30f;
        }

        const bool diag = (j == qt);

        // S = Q K^T
        f32x4 sc[4];
#pragma unroll
        for (int t = 0; t < 4; ++t) sc[t] = (f32x4){0.f, 0.f, 0.f, 0.f};
#pragma unroll
        for (int t = 0; t < 4; ++t) {
            if (diag && t > w) continue;
#pragma unroll
            for (int s = 0; s < 2; ++s) {
                U16x8 kb;
                kb.u4 = *(const uint4*)&Ks[(t * 16 + ln) * ATT_STRIDE + s * 32 + quad * 8];
                sc[t] = __builtin_amdgcn_mfma_f32_16x16x32_bf16(qf[s].b, kb.b, sc[t], 0, 0, 0);
            }
        }

        // pass 1: scale + additive mask + row max
        float rm[4] = {-3.0e38f, -3.0e38f, -3.0e38f, -3.0e38f};
#pragma unroll
        for (int t = 0; t < 4; ++t) {
            if (diag && t > w) {
#pragma unroll
                for (int i = 0; i < 4; ++i) sc[t][i] = -1.0e30f;
            } else {
                const float madd = mask_f[t * 16 + ln];
                const bool edge = diag && (t == w);
#pragma unroll
                for (int i = 0; i < 4; ++i) {
                    float v = fmaf(sc[t][i], 0.125f, madd);
                    if (edge && ln > quad * 4 + i) v = -1.0e30f;
                    sc[t][i] = v;
                    rm[i] = fmaxf(rm[i], v);
                }
            }
        }
#pragma unroll
        for (int i = 0; i < 4; ++i) {
            rm[i] = fmaxf(rm[i], __shfl_xor(rm[i], 1));
            rm[i] = fmaxf(rm[i], __shfl_xor(rm[i], 2));
            rm[i] = fmaxf(rm[i], __shfl_xor(rm[i], 4));
            rm[i] = fmaxf(rm[i], __shfl_xor(rm[i], 8));
        }

        // pass 2: alpha, exp2, per-lane partial sum
        float alpha[4], mlog[4];
#pragma unroll
        for (int i = 0; i < 4; ++i) {
            const float nm = fmaxf(m_i[i], rm[i]);
            alpha[i] = __builtin_amdgcn_exp2f((m_i[i] - nm) * LOG2E);
            m_i[i] = nm;
            mlog[i] = nm * LOG2E;
        }
        float rsp[4] = {0.f, 0.f, 0.f, 0.f};
#pragma unroll
        for (int t = 0; t < 4; ++t)
#pragma unroll
            for (int i = 0; i < 4; ++i) {
                const float p = __builtin_amdgcn_exp2f(fmaf(sc[t][i], LOG2E, -mlog[i]));
                sc[t][i] = p;
                rsp[i] += p;
            }
#pragma unroll
        for (int i = 0; i < 4; ++i) l_i[i] = l_i[i] * alpha[i] + rsp[i];
#pragma unroll
        for (int n = 0; n < 4; ++n)
#pragma unroll
            for (int i = 0; i < 4; ++i) o[n][i] *= alpha[i];

        // P -> LDS -> A-frags
#pragma unroll
        for (int t = 0; t < 4; ++t)
#pragma unroll
            for (int i = 0; i < 4; ++i)
                Ps[(w * 16 + quad * 4 + i) * ATT_STRIDE + t * 16 + ln] = f2bf_fast(sc[t][i]);

        U16x8 pa[2];
        pa[0].u4 = *(const uint4*)&Ps[(w * 16 + ln) * ATT_STRIDE + quad * 8];
        pa[1].u4 = *(const uint4*)&Ps[(w * 16 + ln) * ATT_STRIDE + 32 + quad * 8];

        // O += P V
#pragma unroll
        for (int n = 0; n < 4; ++n)
#pragma unroll
            for (int s = 0; s < 2; ++s) {
                U16x8 vb;
                vb.u4 = *(const uint4*)&Vs[(n * 16 + ln) * ATT_STRIDE + s * 32 + quad * 8];
                o[n] = __builtin_amdgcn_mfma_f32_16x16x32_bf16(pa[s].b, vb.b, o[n], 0, 0, 0);
            }
    }

    // epilogue: reduce partial l across the 16 row-lanes, normalize, store
#pragma unroll
    for (int i = 0; i < 4; ++i) {
        float l = l_i[i];
        l += __shfl_xor(l, 1);
        l += __shfl_xor(l, 2);
        l += __shfl_xor(l, 4);
        l += __shfl_xor(l, 8);
        const float inv = 1.0f / l;
        const size_t row = (size_t)(b * T_SEQ + q0 + w * 16 + quad * 4 + i);
#pragma unroll
        for (int n = 0; n < 4; ++n)
            Y[row * CDIM + h * HD + n * 16 + ln] = f2bf(o[n][i] * inv);
    }
}

// ---------------------------------------------------------------------------
extern "C" void kernel_launch(void* const* d_in, const int* in_sizes, int n_in,
                              void* d_out, int out_size, void* d_ws, size_t ws_size,
                              hipStream_t stream)
{
    const float* X     = (const float*)d_in[0];
    const int*   mask  = (const int*)d_in[1];
    const float* Wqkv  = (const float*)d_in[2];
    const float* bqkv  = (const float*)d_in[3];
    const float* Wproj = (const float*)d_in[4];
    const float* bproj = (const float*)d_in[5];
    float* out = (float*)d_out;

    const size_t per = (size_t)2 * NHEAD * T_SEQ * HD;   // 4,194,304 elems
    unsigned short* Qp     = (unsigned short*)d_ws;
    unsigned short* Kp     = Qp + per;
    unsigned short* Vtp    = Kp + per;
    unsigned short* Xb     = Vtp + per;                  // aliased: Yp reuses Xb
    unsigned short* Yp     = Xb;                         // X consumed before Y written
    unsigned short* Wqkvt  = Xb + per;                   // [3072,1024]
    unsigned short* Wprojt = Wqkvt + (size_t)3 * CDIM * CDIM;  // [1024,1024]

    conv_bf16<<<2048, 256, 0, stream>>>(X, Xb, 4 * 1024 * 1024);
    transpose_conv<<<dim3(16, 48), 256, 0, stream>>>(Wqkv, Wqkvt, CDIM, 3 * CDIM);
    transpose_conv<<<dim3(16, 16), 256, 0, stream>>>(Wproj, Wprojt, CDIM, CDIM);

    qk_gemm<<<dim3(16, 32), 256, 0, stream>>>(Xb, Wqkvt, bqkv, Qp, Kp);
    vt_gemm<<<dim3(32, 8), 256, 0, stream>>>(Wqkvt + (size_t)2048 * CDIM, Xb,
                                             bqkv + 2048, Vtp);
    flash_attn<<<dim3(2 * NHEAD, T_SEQ / 64), 256, 0, stream>>>(Qp, Kp, Vtp, mask, Yp);
    proj_gemm<<<dim3(8, 32), 256, 0, stream>>>(Yp, Wprojt, bproj, out);
}

// Round 11
// 216.176 us; speedup vs baseline: 1.5072x; 1.5072x over previous
//
#include <hip/hip_runtime.h>

#define T_SEQ 2048
#define NHEAD 16
#define HD 64
#define CDIM 1024

typedef __bf16 bf16x8 __attribute__((ext_vector_type(8)));
typedef float f32x4 __attribute__((ext_vector_type(4)));

union U16x8 { uint4 u4; unsigned short s[8]; bf16x8 b; };

__device__ __forceinline__ float bf2f(unsigned short u) {
    return __uint_as_float(((unsigned int)u) << 16);
}
__device__ __forceinline__ unsigned short f2bf(float f) {
    unsigned int u = __float_as_uint(f);
    u += 0x7fffu + ((u >> 16) & 1u);   // round-to-nearest-even
    return (unsigned short)(u >> 16);
}
__device__ __forceinline__ unsigned short f2bf_fast(float f) {   // round-half-up
    return (unsigned short)((__float_as_uint(f) + 0x8000u) >> 16);
}
__device__ __forceinline__ U16x8 load8f(const float* __restrict__ p) {
    U16x8 r;
    float4 f0 = *(const float4*)p;
    float4 f1 = *(const float4*)(p + 4);
    r.s[0] = f2bf(f0.x); r.s[1] = f2bf(f0.y); r.s[2] = f2bf(f0.z); r.s[3] = f2bf(f0.w);
    r.s[4] = f2bf(f1.x); r.s[5] = f2bf(f1.y); r.s[6] = f2bf(f1.z); r.s[7] = f2bf(f1.w);
    return r;
}

// async global->LDS, 16 B per lane; LDS dest = wave-uniform base + lane*16
__device__ __forceinline__ void async_copy16(const unsigned short* g, unsigned short* l) {
    __builtin_amdgcn_global_load_lds(
        (const __attribute__((address_space(1))) unsigned int*)g,
        (__attribute__((address_space(3))) unsigned int*)l, 16, 0, 0);
}

#define LOG2E 1.442695040f

// ---------------------------------------------------------------------------
// Conversion pass
// ---------------------------------------------------------------------------
__global__ __launch_bounds__(256) void conv_bf16(
    const float* __restrict__ in, unsigned short* __restrict__ out, int n)
{
    const int i = (blockIdx.x * 256 + threadIdx.x) * 8;
    if (i < n) {
        U16x8 o = load8f(&in[i]);
        *(uint4*)&out[i] = o.u4;
    }
}

// in: [R,C] fp32 -> out: [C,R] bf16.  R,C multiples of 64.
__global__ __launch_bounds__(256) void transpose_conv(
    const float* __restrict__ in, unsigned short* __restrict__ out, int R, int C)
{
    __shared__ float tile[64][65];
    const int r0 = blockIdx.x * 64;
    const int c0 = blockIdx.y * 64;
    const int tid = threadIdx.x;
    const int rr = tid >> 4;
    const int cc = (tid & 15) * 4;
#pragma unroll
    for (int p = 0; p < 4; ++p) {
        float4 v = *(const float4*)&in[(size_t)(r0 + p * 16 + rr) * C + c0 + cc];
        tile[p * 16 + rr][cc] = v.x;
        tile[p * 16 + rr][cc + 1] = v.y;
        tile[p * 16 + rr][cc + 2] = v.z;
        tile[p * 16 + rr][cc + 3] = v.w;
    }
    __syncthreads();
    const int n = tid >> 2;
    const int s = (tid & 3) * 8;
#pragma unroll
    for (int p = 0; p < 2; ++p) {
        const int k = s + p * 32;
        U16x8 o;
#pragma unroll
        for (int j = 0; j < 8; ++j) o.s[j] = f2bf(tile[k + j][n]);
        *(uint4*)&out[(size_t)(c0 + n) * R + r0 + k] = o.u4;
    }
}

// ---------------------------------------------------------------------------
// m97-style GEMM core (r9 known-good): C[128x128] = A[M,K] * Bt[N,K]^T,
// global_load_lds 16B staging, BK=64, 4x4 acc per wave.
// ---------------------------------------------------------------------------
__device__ __forceinline__ void gemm128_core(
    const unsigned short* __restrict__ A,
    const unsigned short* __restrict__ Bt,
    int K, int m0, int n0,
    unsigned short* As, unsigned short* Bs, f32x4 acc[4][4])
{
    const int tid = threadIdx.x;
    const int w = tid >> 6, lane = tid & 63;
    const int ln = lane & 15, quad = lane >> 4;
    const int wm = w >> 1, wn = w & 1;
    const int lr = lane >> 3;        // 0..7
    const int lc = (lane & 7) * 8;   // col start (elems)

    for (int kb = 0; kb < K; kb += 64) {
        __syncthreads();
#pragma unroll
        for (int i = 0; i < 4; ++i) {
            async_copy16(&A[(size_t)(m0 + w * 32 + i * 8 + lr) * K + kb + lc],
                         &As[(w * 32 + i * 8) * 64]);
            async_copy16(&Bt[(size_t)(n0 + w * 32 + i * 8 + lr) * K + kb + lc],
                         &Bs[(w * 32 + i * 8) * 64]);
        }
        __syncthreads();
#pragma unroll
        for (int kk = 0; kk < 2; ++kk) {
            U16x8 af[4], bff[4];
#pragma unroll
            for (int i = 0; i < 4; ++i)
                af[i].u4 = *(const uint4*)&As[(wm * 64 + i * 16 + ln) * 64 + kk * 32 + quad * 8];
#pragma unroll
            for (int j = 0; j < 4; ++j)
                bff[j].u4 = *(const uint4*)&Bs[(wn * 64 + j * 16 + ln) * 64 + kk * 32 + quad * 8];
#pragma unroll
            for (int i = 0; i < 4; ++i)
#pragma unroll
                for (int j = 0; j < 4; ++j)
                    acc[i][j] = __builtin_amdgcn_mfma_f32_16x16x32_bf16(af[i].b, bff[j].b, acc[i][j], 0, 0, 0);
        }
    }
}

// ---------------------------------------------------------------------------
// Fused QKV: one 768-block dispatch.
//   bid < 512:  Q/K GEMM tile  (n-tile = bid&15 [XCD], m-tile = bid>>4)
//   bid >= 512: V^T GEMM tile  (token-tile = u&31 [XCD], row-tile = u>>5)
// 3 blocks/CU co-resident -> inter-wave overlap hides staging drain.
// ---------------------------------------------------------------------------
__global__ __launch_bounds__(256) void qkv_fused(
    const unsigned short* __restrict__ Xb,    // [4096,1024] bf16
    const unsigned short* __restrict__ Wt,    // [3072,1024] bf16 (W^T; V rows at 2048)
    const float* __restrict__ bias,           // [3072]
    unsigned short* __restrict__ Qp,
    unsigned short* __restrict__ Kp,
    unsigned short* __restrict__ Vtp)         // [B,H,hd,T]
{
    __shared__ unsigned short As[128 * 64];
    __shared__ unsigned short Bs[128 * 64];

    const int bid = blockIdx.x;
    const int tid = threadIdx.x;
    const int w = tid >> 6, lane = tid & 63;
    const int ln = lane & 15, quad = lane >> 4;
    const int wm = w >> 1, wn = w & 1;

    f32x4 acc[4][4];
#pragma unroll
    for (int i = 0; i < 4; ++i)
#pragma unroll
        for (int j = 0; j < 4; ++j) acc[i][j] = (f32x4){0.f, 0.f, 0.f, 0.f};

    if (bid < 512) {
        // ---- Q/K tile ----
        const int n0 = (bid & 15) * 128;       // over Wq|Wk rows (2048)
        const int m0 = (bid >> 4) * 128;       // over tokens (4096)
        gemm128_core(Xb, Wt, CDIM, m0, n0, As, Bs, acc);

#pragma unroll
        for (int j = 0; j < 4; ++j) {
            const int n = n0 + wn * 64 + j * 16 + ln;
            const float bv = bias[n];
            const int which = n >> 10;          // 0=Q, 1=K
            const int h = (n >> 6) & 15, d = n & 63;
            unsigned short* dst = which == 0 ? Qp : Kp;
#pragma unroll
            for (int i = 0; i < 4; ++i)
#pragma unroll
                for (int r = 0; r < 4; ++r) {
                    const int m = m0 + wm * 64 + i * 16 + quad * 4 + r;
                    const int b = m >> 11, tt = m & 2047;
                    dst[(((b * NHEAD + h) * T_SEQ) + tt) * HD + d] = f2bf(acc[i][j][r] + bv);
                }
        }
    } else {
        // ---- V^T tile ----
        const int u = bid - 512;
        const int n0 = (u & 31) * 128;         // tokens (4096)
        const int m0 = (u >> 5) * 128;         // V rows h*64+d (1024)
        const unsigned short* WvT = Wt + (size_t)2048 * CDIM;
        gemm128_core(WvT, Xb, CDIM, m0, n0, As, Bs, acc);

#pragma unroll
        for (int i = 0; i < 4; ++i)
#pragma unroll
            for (int r = 0; r < 4; ++r) {
                const int row = m0 + wm * 64 + i * 16 + quad * 4 + r;   // h*64+d
                const float bv = bias[2048 + row];
#pragma unroll
                for (int j = 0; j < 4; ++j) {
                    const int n = n0 + wn * 64 + j * 16 + ln;           // global token
                    const int b = n >> 11, tt = n & 2047;
                    Vtp[(size_t)(b * 1024 + row) * T_SEQ + tt] = f2bf(acc[i][j][r] + bv);
                }
            }
    }
}

// ---------------------------------------------------------------------------
// Kernel: proj GEMM -> fp32 out.  n-tiles on blockIdx.x (XCD L2).
// ---------------------------------------------------------------------------
__global__ __launch_bounds__(256) void proj_gemm(
    const unsigned short* __restrict__ Yin,   // [4096,1024] bf16
    const unsigned short* __restrict__ Wt,    // [1024,1024] bf16 (W^T)
    const float* __restrict__ bias,           // [1024]
    float* __restrict__ out)                  // [4096,1024] fp32
{
    __shared__ unsigned short As[128 * 64];
    __shared__ unsigned short Bs[128 * 64];
    const int m0 = blockIdx.y * 128;
    const int n0 = blockIdx.x * 128;

    f32x4 acc[4][4];
#pragma unroll
    for (int i = 0; i < 4; ++i)
#pragma unroll
        for (int j = 0; j < 4; ++j) acc[i][j] = (f32x4){0.f, 0.f, 0.f, 0.f};

    gemm128_core(Yin, Wt, CDIM, m0, n0, As, Bs, acc);

    const int tid = threadIdx.x;
    const int w = tid >> 6, lane = tid & 63;
    const int ln = lane & 15, quad = lane >> 4;
    const int wm = w >> 1, wn = w & 1;

#pragma unroll
    for (int j = 0; j < 4; ++j) {
        const int n = n0 + wn * 64 + j * 16 + ln;
        const float bv = bias[n];
#pragma unroll
        for (int i = 0; i < 4; ++i)
#pragma unroll
            for (int r = 0; r < 4; ++r) {
                const int m = m0 + wm * 64 + i * 16 + quad * 4 + r;
                out[(size_t)m * CDIM + n] = acc[i][j][r] + bv;
            }
    }
}

// ---------------------------------------------------------------------------
// MFMA flash attention (unchanged from round 9)
// ---------------------------------------------------------------------------
#define ATT_STRIDE 72

__global__ __launch_bounds__(256) void flash_attn(
    const unsigned short* __restrict__ Qp,   // [BH, T, 64]
    const unsigned short* __restrict__ Kp,   // [BH, T, 64]
    const unsigned short* __restrict__ Vtp,  // [BH, 64, T]
    const int* __restrict__ mask,            // [B, T]
    unsigned short* __restrict__ Y)          // [B*T, 1024] bf16
{
    __shared__ unsigned short Ks[64 * ATT_STRIDE];
    __shared__ unsigned short Vs[64 * ATT_STRIDE];
    __shared__ unsigned short Ps[64 * ATT_STRIDE];
    __shared__ float mask_f[64];

    const int bh = blockIdx.x;                       // XCD locality on K/V
    const int qt = (T_SEQ / 64 - 1) - blockIdx.y;    // heavy first
    const int b = bh >> 4, h = bh & 15;
    const int tid = threadIdx.x;
    const int w = tid >> 6, lane = tid & 63;
    const int ln = lane & 15, quad = lane >> 4;
    const int row8 = tid >> 3, seg = tid & 7;
    const size_t base = (size_t)bh * T_SEQ * HD;
    const int q0 = qt * 64;

    U16x8 qf[2];
    {
        const unsigned short* qrow = &Qp[base + (size_t)(q0 + w * 16 + ln) * HD];
        qf[0].u4 = *(const uint4*)&qrow[quad * 8];
        qf[1].u4 = *(const uint4*)&qrow[32 + quad * 8];
    }

    f32x4 o[4];
#pragma unroll
    for (int n = 0; n < 4; ++n) o[n] = (f32x4){0.f, 0.f, 0.f, 0.f};
    float m_i[4] = {-3.0e38f, -3.0e38f, -3.0e38f, -3.0e38f};
    float l_i[4] = {0.f, 0.f, 0.f, 0.f};   // per-lane PARTIAL sums

    // register prefetch of tile 0
    uint4 kr0, kr1, vr0, vr1;
    float mf = 0.f;
    {
        const unsigned short* kp0 = &Kp[base + (size_t)row8 * HD + seg * 8];
        kr0 = *(const uint4*)kp0;
        kr1 = *(const uint4*)(kp0 + 32 * HD);
        const unsigned short* vp0 = &Vtp[base + (size_t)row8 * T_SEQ + seg * 8];
        vr0 = *(const uint4*)vp0;
        vr1 = *(const uint4*)(vp0 + 32 * T_SEQ);
        if (tid < 64) mf = mask[b * T_SEQ + tid] ? 0.f : -1.0e30f;
    }

    for (int j = 0; j <= qt; ++j) {
        __syncthreads();
        *(uint4*)&Ks[row8 * ATT_STRIDE + seg * 8] = kr0;
        *(uint4*)&Ks[(row8 + 32) * ATT_STRIDE + seg * 8] = kr1;
        *(uint4*)&Vs[row8 * ATT_STRIDE + seg * 8] = vr0;
        *(uint4*)&Vs[(row8 + 32) * ATT_STRIDE + seg * 8] = vr1;
        if (tid < 64) mask_f[tid] = mf;
        __syncthreads();

        if (j < qt) {   // prefetch next tile
            const unsigned short* kp0 = &Kp[base + (size_t)((j + 1) * 64 + row8) * HD + seg * 8];
            kr0 = *(const uint4*)kp0;
            kr1 = *(const uint4*)(kp0 + 32 * HD);
            const unsigned short* vp0 = &Vtp[base + (size_t)row8 * T_SEQ + (j + 1) * 64 + seg * 8];
            vr0 = *(const uint4*)vp0;
            vr1 = *(const uint4*)(vp0 + 32 * T_SEQ);
            if (tid < 64) mf = mask[b * T_SEQ + (j + 1) * 64 + tid] ? 0.f : -1.0e30f;
        }

        const bool diag = (j == qt);

        // S = Q K^T
        f32x4 sc[4];
#pragma unroll
        for (int t = 0; t < 4; ++t) sc[t] = (f32x4){0.f, 0.f, 0.f, 0.f};
#pragma unroll
        for (int t = 0; t < 4; ++t) {
            if (diag && t > w) continue;
#pragma unroll
            for (int s = 0; s < 2; ++s) {
                U16x8 kb;
                kb.u4 = *(const uint4*)&Ks[(t * 16 + ln) * ATT_STRIDE + s * 32 + quad * 8];
                sc[t] = __builtin_amdgcn_mfma_f32_16x16x32_bf16(qf[s].b, kb.b, sc[t], 0, 0, 0);
            }
        }

        // pass 1: scale + additive mask + row max
        float rm[4] = {-3.0e38f, -3.0e38f, -3.0e38f, -3.0e38f};
#pragma unroll
        for (int t = 0; t < 4; ++t) {
            if (diag && t > w) {
#pragma unroll
                for (int i = 0; i < 4; ++i) sc[t][i] = -1.0e30f;
            } else {
                const float madd = mask_f[t * 16 + ln];
                const bool edge = diag && (t == w);
#pragma unroll
                for (int i = 0; i < 4; ++i) {
                    float v = fmaf(sc[t][i], 0.125f, madd);
                    if (edge && ln > quad * 4 + i) v = -1.0e30f;
                    sc[t][i] = v;
                    rm[i] = fmaxf(rm[i], v);
                }
            }
        }
#pragma unroll
        for (int i = 0; i < 4; ++i) {
            rm[i] = fmaxf(rm[i], __shfl_xor(rm[i], 1));
            rm[i] = fmaxf(rm[i], __shfl_xor(rm[i], 2));
            rm[i] = fmaxf(rm[i], __shfl_xor(rm[i], 4));
            rm[i] = fmaxf(rm[i], __shfl_xor(rm[i], 8));
        }

        // pass 2: alpha, exp2, per-lane partial sum
        float alpha[4], mlog[4];
#pragma unroll
        for (int i = 0; i < 4; ++i) {
            const float nm = fmaxf(m_i[i], rm[i]);
            alpha[i] = __builtin_amdgcn_exp2f((m_i[i] - nm) * LOG2E);
            m_i[i] = nm;
            mlog[i] = nm * LOG2E;
        }
        float rsp[4] = {0.f, 0.f, 0.f, 0.f};
#pragma unroll
        for (int t = 0; t < 4; ++t)
#pragma unroll
            for (int i = 0; i < 4; ++i) {
                const float p = __builtin_amdgcn_exp2f(fmaf(sc[t][i], LOG2E, -mlog[i]));
                sc[t][i] = p;
                rsp[i] += p;
            }
#pragma unroll
        for (int i = 0; i < 4; ++i) l_i[i] = l_i[i] * alpha[i] + rsp[i];
#pragma unroll
        for (int n = 0; n < 4; ++n)
#pragma unroll
            for (int i = 0; i < 4; ++i) o[n][i] *= alpha[i];

        // P -> LDS -> A-frags
#pragma unroll
        for (int t = 0; t < 4; ++t)
#pragma unroll
            for (int i = 0; i < 4; ++i)
                Ps[(w * 16 + quad * 4 + i) * ATT_STRIDE + t * 16 + ln] = f2bf_fast(sc[t][i]);

        U16x8 pa[2];
        pa[0].u4 = *(const uint4*)&Ps[(w * 16 + ln) * ATT_STRIDE + quad * 8];
        pa[1].u4 = *(const uint4*)&Ps[(w * 16 + ln) * ATT_STRIDE + 32 + quad * 8];

        // O += P V
#pragma unroll
        for (int n = 0; n < 4; ++n)
#pragma unroll
            for (int s = 0; s < 2; ++s) {
                U16x8 vb;
                vb.u4 = *(const uint4*)&Vs[(n * 16 + ln) * ATT_STRIDE + s * 32 + quad * 8];
                o[n] = __builtin_amdgcn_mfma_f32_16x16x32_bf16(pa[s].b, vb.b, o[n], 0, 0, 0);
            }
    }

    // epilogue: reduce partial l across the 16 row-lanes, normalize, store
#pragma unroll
    for (int i = 0; i < 4; ++i) {
        float l = l_i[i];
        l += __shfl_xor(l, 1);
        l += __shfl_xor(l, 2);
        l += __shfl_xor(l, 4);
        l += __shfl_xor(l, 8);
        const float inv = 1.0f / l;
        const size_t row = (size_t)(b * T_SEQ + q0 + w * 16 + quad * 4 + i);
#pragma unroll
        for (int n = 0; n < 4; ++n)
            Y[row * CDIM + h * HD + n * 16 + ln] = f2bf(o[n][i] * inv);
    }
}

// ---------------------------------------------------------------------------
extern "C" void kernel_launch(void* const* d_in, const int* in_sizes, int n_in,
                              void* d_out, int out_size, void* d_ws, size_t ws_size,
                              hipStream_t stream)
{
    const float* X     = (const float*)d_in[0];
    const int*   mask  = (const int*)d_in[1];
    const float* Wqkv  = (const float*)d_in[2];
    const float* bqkv  = (const float*)d_in[3];
    const float* Wproj = (const float*)d_in[4];
    const float* bproj = (const float*)d_in[5];
    float* out = (float*)d_out;

    const size_t per = (size_t)2 * NHEAD * T_SEQ * HD;   // 4,194,304 elems
    unsigned short* Qp     = (unsigned short*)d_ws;
    unsigned short* Kp     = Qp + per;
    unsigned short* Vtp    = Kp + per;
    unsigned short* Xb     = Vtp + per;                  // aliased: Yp reuses Xb
    unsigned short* Yp     = Xb;                         // X consumed before Y written
    unsigned short* Wqkvt  = Xb + per;                   // [3072,1024]
    unsigned short* Wprojt = Wqkvt + (size_t)3 * CDIM * CDIM;  // [1024,1024]

    conv_bf16<<<2048, 256, 0, stream>>>(X, Xb, 4 * 1024 * 1024);
    transpose_conv<<<dim3(16, 48), 256, 0, stream>>>(Wqkv, Wqkvt, CDIM, 3 * CDIM);
    transpose_conv<<<dim3(16, 16), 256, 0, stream>>>(Wproj, Wprojt, CDIM, CDIM);

    qkv_fused<<<768, 256, 0, stream>>>(Xb, Wqkvt, bqkv, Qp, Kp, Vtp);
    flash_attn<<<dim3(2 * NHEAD, T_SEQ / 64), 256, 0, stream>>>(Qp, Kp, Vtp, mask, Yp);
    proj_gemm<<<dim3(8, 32), 256, 0, stream>>>(Yp, Wprojt, bproj, out);
}